// Round 1
// baseline (576.294 us; speedup 1.0000x reference)
//
#include <hip/hip_runtime.h>

// Problem: out_fp = (a*scale_a) * (b*scale_b); out_q = clip(round(out_fp/scale_out), -128, 127)
// a,b: int8 in reference, delivered as int32 (const int*), shape (B,S,D)=(16,4096,1024) flat N=67108864.
// scales: float32, (D,)=1024.
// d_out: float* holding N quantized values (as floats) followed by D scale_out values.
//
// Memory-bound: 512 MiB read + 256 MiB write => ~128 us floor at 6.3 TB/s.

__global__ void prep_scales_kernel(const float* __restrict__ sa,
                                   const float* __restrict__ sb,
                                   const float* __restrict__ so,
                                   float* __restrict__ c,
                                   float* __restrict__ out_tail,
                                   int D) {
    int d = blockIdx.x * blockDim.x + threadIdx.x;
    if (d < D) {
        float s = so[d];
        c[d] = sa[d] * sb[d] / s;   // exact IEEE divide, once per column
        out_tail[d] = s;            // second tuple output: scale_out passthrough
    }
}

__global__ __launch_bounds__(256) void mulq_kernel(const int4* __restrict__ a,
                                                   const int4* __restrict__ b,
                                                   const float* __restrict__ c,
                                                   float4* __restrict__ out,
                                                   unsigned dmask, unsigned use_mask,
                                                   unsigned D, unsigned nvec) {
    unsigned tid = blockIdx.x * blockDim.x + threadIdx.x;
    if (tid >= nvec) return;
    unsigned e0 = tid * 4u;                         // first element index of this thread
    unsigned d = use_mask ? (e0 & dmask) : (e0 % D); // column index (multiple of 4)

    int4 av = a[tid];                               // 16B coalesced load
    int4 bv = b[tid];                               // 16B coalesced load
    float4 cv = *(const float4*)(c + d);            // 4KB working set, L1-resident

    float4 o;
    o.x = fminf(fmaxf(rintf((float)(av.x * bv.x) * cv.x), -128.0f), 127.0f);
    o.y = fminf(fmaxf(rintf((float)(av.y * bv.y) * cv.y), -128.0f), 127.0f);
    o.z = fminf(fmaxf(rintf((float)(av.z * bv.z) * cv.z), -128.0f), 127.0f);
    o.w = fminf(fmaxf(rintf((float)(av.w * bv.w) * cv.w), -128.0f), 127.0f);

    out[tid] = o;                                   // 16B coalesced store
}

extern "C" void kernel_launch(void* const* d_in, const int* in_sizes, int n_in,
                              void* d_out, int out_size, void* d_ws, size_t ws_size,
                              hipStream_t stream) {
    const int*   a  = (const int*)  d_in[0];
    const float* sa = (const float*)d_in[1];
    const int*   b  = (const int*)  d_in[2];
    const float* sb = (const float*)d_in[3];
    const float* so = (const float*)d_in[4];

    const int N = in_sizes[0];   // 67108864 (multiple of D, D multiple of 4)
    const int D = in_sizes[1];   // 1024

    float* out = (float*)d_out;
    float* c   = (float*)d_ws;   // D floats of scratch (4 KiB)

    // Fold scales + write scale_out tail (out[N .. N+D)).
    prep_scales_kernel<<<(D + 255) / 256, 256, 0, stream>>>(sa, sb, so, c, out + (size_t)N, D);

    const unsigned nvec = (unsigned)(N / 4);
    const unsigned use_mask = ((D & (D - 1)) == 0) ? 1u : 0u;
    mulq_kernel<<<(nvec + 255) / 256, 256, 0, stream>>>(
        (const int4*)a, (const int4*)b, c, (float4*)out,
        (unsigned)(D - 1), use_mask, (unsigned)D, nvec);
}